// Round 5
// baseline (229.121 us; speedup 1.0000x reference)
//
#include <hip/hip_runtime.h>

// ---------------------------------------------------------------------------
// MultiScaleResidualVectorQuantize: 4-stage residual VQ, strides (8,4,2,1)
// Algebraic restructure: e_i = P_i - sum_{j<i} (M_ij q_j + v_ij) with
// P_i = iw_i * pool_i(z) + ib_i,  M_ij = iw_i*ow_j (8x8),  v_ij = iw_i*ob_j.
// One read of z, one write of z_q; cascade entirely in C=8 space.
// VQ cascade fused into ONE kernel: block owns 32 stride-8 windows; all
// stage dependencies are window-local -> LDS + block barriers only.
// ---------------------------------------------------------------------------

constexpr int B = 16, D = 512, T = 4096, C = 8, K = 1024, NS = 4;

// output offsets (floats, concatenated in reference return order)
constexpr long long OUT_ZQ     = 0;                       // 16*512*4096
constexpr long long OUT_LAT    = 33554432LL;              // 16*32*4096
constexpr long long OUT_COMMIT = OUT_LAT + 2097152LL;     // 35651584
constexpr long long OUT_CBL    = OUT_COMMIT + 1;          // 35651585
constexpr long long OUT_CODES0 = OUT_CBL + 1;             // 35651586

// workspace offsets (floats)
constexpr long long WS_CBREC = 0;                 // 4*1024*12
constexpr long long WS_OBS   = 49152;             // 512 (sum of out biases)
constexpr long long WS_LOSS  = 49664;             // 1
constexpr long long WS_CORR  = 49696;             // doubles: 6 pairs * 72
constexpr long long WS_P0    = 52224;             // 8192*8
constexpr long long WS_P1    = WS_P0 + 65536;
constexpr long long WS_P2    = WS_P1 + 131072;
constexpr long long WS_P3    = WS_P2 + 262144;
constexpr long long WS_Q0    = WS_P3 + 524288;
constexpr long long WS_Q1    = WS_Q0 + 65536;
constexpr long long WS_Q2    = WS_Q1 + 131072;
constexpr long long WS_Q3    = WS_Q2 + 262144;    // ends ~8.1 MB

// ---------------------------------------------------------------------------
// k_prep (merged): blocks 0..17 -> codebook records + summed bias + loss=0;
// blocks 18..125 -> correction terms M_ij/v_ij in f64 (one wave per scalar).
// ---------------------------------------------------------------------------
__global__ __launch_bounds__(256) void k_prep(
    const float* __restrict__ in_w, const float* __restrict__ out_w,
    const float* __restrict__ out_b, const float* __restrict__ cb,
    float* __restrict__ ws)
{
    int bid = blockIdx.x;
    int tid = threadIdx.x;

    if (bid < 18) {
        int t = bid * 256 + tid;
        if (t == 0) ws[WS_LOSS] = 0.f;
        if (t < NS * K) {
            const float* c = cb + (long long)t * 8;
            float cv[8];
#pragma unroll
            for (int k = 0; k < 8; k++) cv[k] = c[k];
            float n2 = 0.f;
#pragma unroll
            for (int k = 0; k < 8; k++) n2 += cv[k] * cv[k];
            float den = fmaxf(sqrtf(n2), 1e-12f);
            float cn[8];
#pragma unroll
            for (int k = 0; k < 8; k++) cn[k] = cv[k] / den;
            float cn2 = 0.f;
#pragma unroll
            for (int k = 0; k < 8; k++) cn2 += cn[k] * cn[k];
            float* r = ws + WS_CBREC + (long long)t * 12;
#pragma unroll
            for (int k = 0; k < 8; k++) r[k] = -2.0f * cn[k];
            r[8] = cn2; r[9] = 0.f; r[10] = 0.f; r[11] = 0.f;
        } else if (t < NS * K + D) {
            int d = t - NS * K;
            ws[WS_OBS + d] = out_b[d] + out_b[512 + d] + out_b[1024 + d] + out_b[1536 + d];
        }
        return;
    }

    int gw = (bid - 18) * 4 + (tid >> 6);
    int lane = tid & 63;
    if (gw >= 6 * 72) return;
    int p = gw / 72, idx = gw % 72;
    int i, j;
    if (p == 0) { i = 1; j = 0; }
    else if (p < 3) { i = 2; j = p - 1; }
    else { i = 3; j = p - 3; }

    double acc = 0.0;
    if (idx < 64) {
        int ci = idx >> 3, cc = idx & 7;
        const float* wi = in_w + (long long)(i * 8 + ci) * 512;
        const float* wo = out_w + (long long)j * 4096;      // [d][8]
#pragma unroll
        for (int k = 0; k < 8; k++) {
            int d = lane + k * 64;
            acc += (double)wi[d] * (double)wo[d * 8 + cc];
        }
    } else {
        int ci = idx - 64;
        const float* wi = in_w + (long long)(i * 8 + ci) * 512;
        const float* bo = out_b + (long long)j * 512;
#pragma unroll
        for (int k = 0; k < 8; k++) {
            int d = lane + k * 64;
            acc += (double)wi[d] * (double)bo[d];
        }
    }
#pragma unroll
    for (int off = 32; off >= 1; off >>= 1) acc += __shfl_down(acc, off);
    if (lane == 0) ((double*)(ws + WS_CORR))[p * 72 + idx] = acc;
}

// ---------------------------------------------------------------------------
// k_pool_proj v3 (unchanged from R4): 72KB LDS aliased, 512 blocks.
// ---------------------------------------------------------------------------
__global__ __launch_bounds__(512) void k_pool_proj(
    const float* __restrict__ z, const float* __restrict__ in_w,
    const float* __restrict__ in_b, float* __restrict__ ws)
{
    __shared__ float smem[512 * 36];     // 72 KB: in_w [d][36], later reduction tree

    int tid = threadIdx.x;
    int lane = tid & 63;
    int wv = __builtin_amdgcn_readfirstlane(tid >> 6);   // dseg, wave-uniform
    int b = blockIdx.x;
    int t0 = blockIdx.y * 128;

    // stage in_w -> LDS transposed
#pragma unroll
    for (int sc = 0; sc < 32; ++sc)
        smem[tid * 36 + sc] = in_w[sc * 512 + tid];
    __syncthreads();

    const float* zrow = z + ((long long)b * D) * T + t0 + lane * 2;

    float a3[2][8] = {};
    float a2[8]    = {};
    float a1[8]    = {};
    float a0[8]    = {};

#pragma unroll 2
    for (int dd = 0; dd < 64; dd++) {
        int d = wv * 64 + dd;
        float2 v = *(const float2*)(zrow + (long long)d * T);
        const float* wrow = smem + d * 36;
        float w0[8], w1[8], w2[8], w3[8];
        *(float4*)&w0[0] = *(const float4*)(wrow + 0);
        *(float4*)&w0[4] = *(const float4*)(wrow + 4);
        *(float4*)&w1[0] = *(const float4*)(wrow + 8);
        *(float4*)&w1[4] = *(const float4*)(wrow + 12);
        *(float4*)&w2[0] = *(const float4*)(wrow + 16);
        *(float4*)&w2[4] = *(const float4*)(wrow + 20);
        *(float4*)&w3[0] = *(const float4*)(wrow + 24);
        *(float4*)&w3[4] = *(const float4*)(wrow + 28);

        float s2 = v.x + v.y;
#pragma unroll
        for (int c = 0; c < 8; c++) {
            a3[0][c] = fmaf(w3[c], v.x, a3[0][c]);
            a3[1][c] = fmaf(w3[c], v.y, a3[1][c]);
            a2[c]    = fmaf(w2[c], s2, a2[c]);
            a1[c]    = fmaf(w1[c], s2, a1[c]);
            a0[c]    = fmaf(w0[c], s2, a0[c]);
        }
    }

    __syncthreads();

    {
        float (*red)[16][64] = (float (*)[16][64])smem;
#pragma unroll
        for (int pos = 0; pos < 2; pos++)
#pragma unroll
            for (int c = 0; c < 8; c++)
                red[wv][pos * 8 + c][lane] = a3[pos][c];
        __syncthreads();
        for (int o = tid; o < 1024; o += 512) {
            int ln = o & 63, s = o >> 6;
            float sum = 0.f;
#pragma unroll
            for (int w = 0; w < 8; w++) sum += red[w][s][ln];
            int pos = s >> 3, c = s & 7;
            int tp = t0 + ln * 2 + pos;
            ws[WS_P3 + ((long long)b * 4096 + tp) * 8 + c] = sum + in_b[3 * 8 + c];
        }
        __syncthreads();
    }

    {
        float (*red)[24][64] = (float (*)[24][64])smem;
#pragma unroll
        for (int c = 0; c < 8; c++) {
            red[wv][c][lane]      = a2[c];
            red[wv][8 + c][lane]  = a1[c];
            red[wv][16 + c][lane] = a0[c];
        }
        __syncthreads();
        for (int o = tid; o < 1536; o += 512) {
            int ln = o & 63, s = o >> 6;
            if (s < 8) {
                int c = s;
                float sum = 0.f;
#pragma unroll
                for (int w = 0; w < 8; w++) sum += red[w][s][ln];
                int tp = (t0 >> 1) + ln;
                ws[WS_P2 + ((long long)b * 2048 + tp) * 8 + c] = sum * 0.5f + in_b[2 * 8 + c];
            } else if (s < 16) {
                if (ln >= 32) continue;
                int c = s - 8;
                float sum = 0.f;
#pragma unroll
                for (int w = 0; w < 8; w++) sum += red[w][s][2 * ln] + red[w][s][2 * ln + 1];
                int tp = (t0 >> 2) + ln;
                ws[WS_P1 + ((long long)b * 1024 + tp) * 8 + c] = sum * 0.25f + in_b[8 + c];
            } else {
                if (ln >= 16) continue;
                int c = s - 16;
                float sum = 0.f;
#pragma unroll
                for (int w = 0; w < 8; w++)
#pragma unroll
                    for (int k = 0; k < 4; k++) sum += red[w][s][4 * ln + k];
                int tp = (t0 >> 3) + ln;
                ws[WS_P0 + ((long long)b * 512 + tp) * 8 + c] = sum * 0.125f + in_b[c];
            }
        }
    }
}

// ---------------------------------------------------------------------------
// k_vq_fused: one block = 32 stride-8 windows (all 4 stages, window-local
// deps). 512 thr = 8 waves; per pass: lane owns a vector, wave scans a
// 128-code chunk; LDS argmin reduce; q's live in LDS for corrections.
// Stage-end: coalesced latents/codes/Q writes from LDS. 1 loss atomic/block.
// ---------------------------------------------------------------------------
template <int S>
__device__ __forceinline__ void vq_stage(
    int tid, int lane, int w, int b, int wt0,
    const float* __restrict__ cb, float* __restrict__ ws, float* __restrict__ out,
    float (&q0l)[32][9], float (&q1l)[64][9], float (&q2l)[128][9],
    float (*qsl)[9],                       // this stage's q LDS
    float (&e_lds)[256][9], int (&idx_lds)[256],
    float (&sb)[8][64], int (&si)[8][64],
    float& loss_acc)
{
    constexpr int TS = 512 << S;
    constexpr int NV = 32 << S;                       // vectors per block this stage
    constexpr int NPASS = (NV > 64) ? NV / 64 : 1;
    constexpr long long PBASE = (S == 0) ? WS_P0 : (S == 1) ? WS_P1 : (S == 2) ? WS_P2 : WS_P3;
    constexpr long long QBASE = (S == 0) ? WS_Q0 : (S == 1) ? WS_Q1 : (S == 2) ? WS_Q2 : WS_Q3;
    constexpr long long CODE_OFF = OUT_CODES0 + ((S >= 1) ? 8192 : 0)
                                   + ((S >= 2) ? 16384 : 0) + ((S >= 3) ? 32768 : 0);
    constexpr int pbase = (S == 1) ? 0 : (S == 2) ? 1 : 3;
    constexpr float LW = 1.0f / (8.0f * (float)TS * (float)B);

    for (int pass = 0; pass < NPASS; ++pass) {
        int sv = (NV >= 64) ? (pass * 64 + lane) : (lane & (NV - 1));
        int wl = sv >> S;
        int pos = sv & ((1 << S) - 1);
        int tp = (wt0 + wl) * (1 << S) + pos;
        long long v = (long long)b * TS + tp;

        // e = P - corrections (f64)
        float e[8];
        const float* P = ws + PBASE + v * 8;
#pragma unroll
        for (int c = 0; c < 8; c++) e[c] = P[c];

        if (S > 0) {
            double ed[8];
#pragma unroll
            for (int c = 0; c < 8; c++) ed[c] = (double)e[c];
            const double* corr = (const double*)(ws + WS_CORR);
#pragma unroll
            for (int j = 0; j < S; j++) {
                const double* M = corr + (pbase + j) * 72;
                const float* ql = (j == 0) ? q0l[sv >> S]
                                : (j == 1) ? q1l[sv >> (S - 1)]
                                           : q2l[sv >> (S - 2)];
#pragma unroll
                for (int c = 0; c < 8; c++) {
                    double acc = M[64 + c];
#pragma unroll
                    for (int cc = 0; cc < 8; cc++) acc += M[c * 8 + cc] * (double)ql[cc];
                    ed[c] -= acc;
                }
            }
#pragma unroll
            for (int c = 0; c < 8; c++) e[c] = (float)ed[c];
        }

        // normalize
        float n2 = 0.f;
#pragma unroll
        for (int c = 0; c < 8; c++) n2 = fmaf(e[c], e[c], n2);
        float den = fmaxf(sqrtf(n2), 1e-12f);
        float inv = 1.0f / den;
        float en[8];
#pragma unroll
        for (int c = 0; c < 8; c++) en[c] = e[c] * inv;

        if (w == 0) {
#pragma unroll
            for (int c = 0; c < 8; c++) e_lds[sv][c] = e[c];
        }

        // scan wave's 128-code chunk (en2 const per vector -> dropped)
        const float* rec = ws + WS_CBREC + (long long)S * K * 12 + (long long)w * 128 * 12;
        float best = 3.0e38f;
        int bidx = 0;
        for (int jt = 0; jt < 128; jt++) {
            const float* r = rec + jt * 12;
            float acc = r[8];                       // cn2
#pragma unroll
            for (int c = 0; c < 8; c++) acc = fmaf(r[c], en[c], acc);  // - 2*dot
            if (acc < best) { best = acc; bidx = w * 128 + jt; }
        }
        sb[w][lane] = best;
        si[w][lane] = bidx;
        __syncthreads();

        if (tid < 64 && lane < ((NV >= 64) ? 64 : NV)) {
            float bd = sb[0][lane];
            int bj = si[0][lane];
#pragma unroll
            for (int ww = 1; ww < 8; ww++) {
                float d2 = sb[ww][lane];
                int j2 = si[ww][lane];
                if (d2 < bd || (d2 == bd && j2 < bj)) { bd = d2; bj = j2; }
            }
            const float* qc = cb + ((long long)S * K + bj) * 8;
            float l2 = 0.f;
#pragma unroll
            for (int c = 0; c < 8; c++) {
                float qv = qc[c];
                qsl[sv][c] = qv;
                float dq = e[c] - qv;
                l2 = fmaf(dq, dq, l2);
            }
            idx_lds[sv] = bj;
            loss_acc += l2 * LW;
        }
        __syncthreads();
    }

    // ---- stage-end cooperative, coalesced outputs ----
    long long v0 = (long long)b * TS + (long long)wt0 * (1 << S);
    // codes
    for (int o = tid; o < NV; o += 512)
        out[CODE_OFF + v0 + o] = (float)idx_lds[o];
    // Q -> ws (for k_zq)
    for (int o = tid; o < NV * 8; o += 512)
        ws[QBASE + v0 * 8 + o] = qsl[o >> 3][o & 7];
    // latents (always 256 t-positions per block per stage)
    long long lat0 = OUT_LAT + ((long long)b * 32 + S * 8) * T + (long long)wt0 * 8;
    for (int o = tid; o < 8 * 256; o += 512) {
        int c = o >> 8, i = o & 255;
        out[lat0 + (long long)c * T + i] = e_lds[i >> (3 - S)][c];
    }
    __syncthreads();
}

__global__ __launch_bounds__(512) void k_vq_fused(
    const float* __restrict__ cb, float* __restrict__ ws, float* __restrict__ out)
{
    __shared__ float q0l[32][9];
    __shared__ float q1l[64][9];
    __shared__ float q2l[128][9];
    __shared__ float q3l[256][9];
    __shared__ float e_lds[256][9];
    __shared__ int   idx_lds[256];
    __shared__ float sb[8][64];
    __shared__ int   si[8][64];

    int tid = threadIdx.x;
    int lane = tid & 63;
    int w = __builtin_amdgcn_readfirstlane(tid >> 6);
    int b = blockIdx.x >> 4;                 // 256 blocks = 16 b x 16 window-groups
    int wt0 = (blockIdx.x & 15) * 32;
    float loss_acc = 0.f;

    vq_stage<0>(tid, lane, w, b, wt0, cb, ws, out, q0l, q1l, q2l, q0l, e_lds, idx_lds, sb, si, loss_acc);
    vq_stage<1>(tid, lane, w, b, wt0, cb, ws, out, q0l, q1l, q2l, q1l, e_lds, idx_lds, sb, si, loss_acc);
    vq_stage<2>(tid, lane, w, b, wt0, cb, ws, out, q0l, q1l, q2l, q2l, e_lds, idx_lds, sb, si, loss_acc);
    vq_stage<3>(tid, lane, w, b, wt0, cb, ws, out, q0l, q1l, q2l, q3l, e_lds, idx_lds, sb, si, loss_acc);

    if (tid < 64) {
#pragma unroll
        for (int off = 32; off >= 1; off >>= 1) loss_acc += __shfl_down(loss_acc, off);
        if (lane == 0) atomicAdd(ws + WS_LOSS, loss_acc);
    }
}

// ---------------------------------------------------------------------------
// k_zq v3 (unchanged from R4): lane owns 4 t -> float4 stores; 4096 blocks.
// ---------------------------------------------------------------------------
__global__ __launch_bounds__(256) void k_zq(
    const float* __restrict__ out_w, const float* __restrict__ ws, float* __restrict__ out)
{
    int tid = threadIdx.x;
    int lane = tid & 63;
    int w = __builtin_amdgcn_readfirstlane(tid >> 6);
    int bid = blockIdx.x;                 // 4096 = 16 b * 64 dgrp * 4 tchunk
    int tc   = bid & 3;
    int g    = (bid >> 2) & 63;
    int b    = bid >> 8;
    int t    = tc * 1024 + w * 256 + lane * 4;

    float q0[8], q1[8], q2[2][8], q3[4][8];
    {
        const float* Q = ws + WS_Q0 + ((long long)b * 512 + (t >> 3)) * 8;
#pragma unroll
        for (int c = 0; c < 8; c++) q0[c] = Q[c];
    }
    {
        const float* Q = ws + WS_Q1 + ((long long)b * 1024 + (t >> 2)) * 8;
#pragma unroll
        for (int c = 0; c < 8; c++) q1[c] = Q[c];
    }
    {
        const float* Q = ws + WS_Q2 + ((long long)b * 2048 + (t >> 1)) * 8;
#pragma unroll
        for (int j = 0; j < 2; j++)
#pragma unroll
            for (int c = 0; c < 8; c++) q2[j][c] = Q[j * 8 + c];
    }
    {
        const float* Q = ws + WS_Q3 + ((long long)b * 4096 + t) * 8;
#pragma unroll
        for (int j = 0; j < 4; j++)
#pragma unroll
            for (int c = 0; c < 8; c++) q3[j][c] = Q[j * 8 + c];
    }

#pragma unroll 2
    for (int dl = 0; dl < 8; dl++) {
        int d = g * 8 + dl;
        const float* w0 = out_w + 0 * 4096 + d * 8;
        const float* w1 = out_w + 1 * 4096 + d * 8;
        const float* w2 = out_w + 2 * 4096 + d * 8;
        const float* w3 = out_w + 3 * 4096 + d * 8;

        float acc = ws[WS_OBS + d];
#pragma unroll
        for (int c = 0; c < 8; c++) acc = fmaf(w0[c], q0[c], acc);
#pragma unroll
        for (int c = 0; c < 8; c++) acc = fmaf(w1[c], q1[c], acc);
        float accA = acc, accB = acc;
#pragma unroll
        for (int c = 0; c < 8; c++) {
            accA = fmaf(w2[c], q2[0][c], accA);
            accB = fmaf(w2[c], q2[1][c], accB);
        }
        float r0 = accA, r1 = accA, r2 = accB, r3 = accB;
#pragma unroll
        for (int c = 0; c < 8; c++) {
            r0 = fmaf(w3[c], q3[0][c], r0);
            r1 = fmaf(w3[c], q3[1][c], r1);
            r2 = fmaf(w3[c], q3[2][c], r2);
            r3 = fmaf(w3[c], q3[3][c], r3);
        }
        float* o = out + OUT_ZQ + ((long long)b * 512 + d) * T + t;
        *(float4*)o = make_float4(r0, r1, r2, r3);
    }

    if (bid == 0 && tid == 0) {
        float L = ws[WS_LOSS];
        out[OUT_COMMIT] = L;
        out[OUT_CBL]    = L;
    }
}

// ---------------------------------------------------------------------------
extern "C" void kernel_launch(void* const* d_in, const int* in_sizes, int n_in,
                              void* d_out, int out_size, void* d_ws, size_t ws_size,
                              hipStream_t stream)
{
    const float* z     = (const float*)d_in[0];
    const float* in_w  = (const float*)d_in[1];
    const float* in_b  = (const float*)d_in[2];
    const float* out_w = (const float*)d_in[3];
    const float* out_b = (const float*)d_in[4];
    const float* cb    = (const float*)d_in[5];
    float* out = (float*)d_out;
    float* ws  = (float*)d_ws;

    k_prep<<<dim3(126), dim3(256), 0, stream>>>(in_w, out_w, out_b, cb, ws);
    k_pool_proj<<<dim3(16, 32), dim3(512), 0, stream>>>(z, in_w, in_b, ws);
    k_vq_fused<<<dim3(256), dim3(512), 0, stream>>>(cb, ws, out);
    k_zq<<<dim3(4096), dim3(256), 0, stream>>>(out_w, ws, out);
}

// Round 6
// 151.087 us; speedup vs baseline: 1.5165x; 1.5165x over previous
//
#include <hip/hip_runtime.h>

// ---------------------------------------------------------------------------
// MultiScaleResidualVectorQuantize: 4-stage residual VQ, strides (8,4,2,1)
// e_i = P_i - sum_{j<i} tab_ij[idx_j]  with P_i = iw_i*pool_i(z)+ib_i and
// tab_ij[code] = M_ij*cb_j[code] + v_ij  (M_ij = iw_i*ow_j, v_ij = iw_i*ob_j,
// precomputed in f64, stored f32). One read of z, one write of z_q; cascade
// entirely in C=8 space. VQ: per-stage kernels, codebook records in LDS.
// ---------------------------------------------------------------------------

constexpr int B = 16, D = 512, T = 4096, C = 8, K = 1024, NS = 4;

// output offsets (floats, concatenated in reference return order)
constexpr long long OUT_ZQ     = 0;                       // 16*512*4096
constexpr long long OUT_LAT    = 33554432LL;              // 16*32*4096
constexpr long long OUT_COMMIT = OUT_LAT + 2097152LL;     // 35651584
constexpr long long OUT_CBL    = OUT_COMMIT + 1;          // 35651585
constexpr long long OUT_CODES0 = OUT_CBL + 1;             // 35651586

__host__ __device__ constexpr long long code_off(int j) {
    return OUT_CODES0 + (j >= 1 ? 8192 : 0) + (j >= 2 ? 16384 : 0) + (j >= 3 ? 32768 : 0);
}

// workspace offsets (floats)
constexpr long long WS_CBREC = 0;                 // 4*1024*12
constexpr long long WS_OBS   = 49152;             // 512 (sum of out biases)
constexpr long long WS_LOSS  = 49664;             // 1
constexpr long long WS_CORR  = 49696;             // doubles: 6 pairs * 72
constexpr long long WS_P0    = 52224;             // 8192*8
constexpr long long WS_P1    = WS_P0 + 65536;
constexpr long long WS_P2    = WS_P1 + 131072;
constexpr long long WS_P3    = WS_P2 + 262144;
constexpr long long WS_Q0    = WS_P3 + 524288;
constexpr long long WS_Q1    = WS_Q0 + 65536;
constexpr long long WS_Q2    = WS_Q1 + 131072;
constexpr long long WS_Q3    = WS_Q2 + 262144;
constexpr long long WS_TAB   = WS_Q3 + 524288;    // 6*1024*8 f32; ends 2,067,456 (~8.27MB)

// ---------------------------------------------------------------------------
// k_prep (merged): blocks 0..17 -> codebook records + summed bias + loss=0;
// blocks 18..125 -> correction terms M_ij/v_ij in f64 (one wave per scalar).
// ---------------------------------------------------------------------------
__global__ __launch_bounds__(256) void k_prep(
    const float* __restrict__ in_w, const float* __restrict__ out_w,
    const float* __restrict__ out_b, const float* __restrict__ cb,
    float* __restrict__ ws)
{
    int bid = blockIdx.x;
    int tid = threadIdx.x;

    if (bid < 18) {
        int t = bid * 256 + tid;
        if (t == 0) ws[WS_LOSS] = 0.f;
        if (t < NS * K) {
            const float* c = cb + (long long)t * 8;
            float cv[8];
#pragma unroll
            for (int k = 0; k < 8; k++) cv[k] = c[k];
            float n2 = 0.f;
#pragma unroll
            for (int k = 0; k < 8; k++) n2 += cv[k] * cv[k];
            float den = fmaxf(sqrtf(n2), 1e-12f);
            float cn[8];
#pragma unroll
            for (int k = 0; k < 8; k++) cn[k] = cv[k] / den;
            float cn2 = 0.f;
#pragma unroll
            for (int k = 0; k < 8; k++) cn2 += cn[k] * cn[k];
            float* r = ws + WS_CBREC + (long long)t * 12;
#pragma unroll
            for (int k = 0; k < 8; k++) r[k] = -2.0f * cn[k];
            r[8] = cn2; r[9] = 0.f; r[10] = 0.f; r[11] = 0.f;
        } else if (t < NS * K + D) {
            int d = t - NS * K;
            ws[WS_OBS + d] = out_b[d] + out_b[512 + d] + out_b[1024 + d] + out_b[1536 + d];
        }
        return;
    }

    int gw = (bid - 18) * 4 + (tid >> 6);
    int lane = tid & 63;
    if (gw >= 6 * 72) return;
    int p = gw / 72, idx = gw % 72;
    int i, j;
    if (p == 0) { i = 1; j = 0; }
    else if (p < 3) { i = 2; j = p - 1; }
    else { i = 3; j = p - 3; }

    double acc = 0.0;
    if (idx < 64) {
        int ci = idx >> 3, cc = idx & 7;
        const float* wi = in_w + (long long)(i * 8 + ci) * 512;
        const float* wo = out_w + (long long)j * 4096;      // [d][8]
#pragma unroll
        for (int k = 0; k < 8; k++) {
            int d = lane + k * 64;
            acc += (double)wi[d] * (double)wo[d * 8 + cc];
        }
    } else {
        int ci = idx - 64;
        const float* wi = in_w + (long long)(i * 8 + ci) * 512;
        const float* bo = out_b + (long long)j * 512;
#pragma unroll
        for (int k = 0; k < 8; k++) {
            int d = lane + k * 64;
            acc += (double)wi[d] * (double)bo[d];
        }
    }
#pragma unroll
    for (int off = 32; off >= 1; off >>= 1) acc += __shfl_down(acc, off);
    if (lane == 0) ((double*)(ws + WS_CORR))[p * 72 + idx] = acc;
}

// ---------------------------------------------------------------------------
// k_prep_c: correction gather tables. tab[p][code][c] =
// f32( v[p][c] + sum_cc M[p][c][cc]*cb_j[code][cc] ), f64 inner. One thread
// per (p,code). pairs p: (1,0),(2,0),(2,1),(3,0),(3,1),(3,2) -> j = source stage.
// ---------------------------------------------------------------------------
__global__ __launch_bounds__(256) void k_prep_c(
    const float* __restrict__ cb, float* __restrict__ ws)
{
    int t = blockIdx.x * 256 + threadIdx.x;
    if (t >= 6 * 1024) return;
    int p = t >> 10, code = t & 1023;
    int j = (p == 0) ? 0 : (p < 3) ? (p - 1) : (p - 3);
    const double* M = (const double*)(ws + WS_CORR) + p * 72;
    const float* q = cb + ((long long)j * K + code) * 8;
    float qv[8];
#pragma unroll
    for (int cc = 0; cc < 8; cc++) qv[cc] = q[cc];
    float* trow = ws + WS_TAB + (long long)t * 8;
#pragma unroll
    for (int c = 0; c < 8; c++) {
        double acc = M[64 + c];
#pragma unroll
        for (int cc = 0; cc < 8; cc++) acc += M[c * 8 + cc] * (double)qv[cc];
        trow[c] = (float)acc;
    }
}

// ---------------------------------------------------------------------------
// k_pool_proj (unchanged from R4): 72KB LDS aliased, 512 blocks.
// ---------------------------------------------------------------------------
__global__ __launch_bounds__(512) void k_pool_proj(
    const float* __restrict__ z, const float* __restrict__ in_w,
    const float* __restrict__ in_b, float* __restrict__ ws)
{
    __shared__ float smem[512 * 36];     // 72 KB: in_w [d][36], later reduction tree

    int tid = threadIdx.x;
    int lane = tid & 63;
    int wv = __builtin_amdgcn_readfirstlane(tid >> 6);
    int b = blockIdx.x;
    int t0 = blockIdx.y * 128;

#pragma unroll
    for (int sc = 0; sc < 32; ++sc)
        smem[tid * 36 + sc] = in_w[sc * 512 + tid];
    __syncthreads();

    const float* zrow = z + ((long long)b * D) * T + t0 + lane * 2;

    float a3[2][8] = {};
    float a2[8]    = {};
    float a1[8]    = {};
    float a0[8]    = {};

#pragma unroll 2
    for (int dd = 0; dd < 64; dd++) {
        int d = wv * 64 + dd;
        float2 v = *(const float2*)(zrow + (long long)d * T);
        const float* wrow = smem + d * 36;
        float w0[8], w1[8], w2[8], w3[8];
        *(float4*)&w0[0] = *(const float4*)(wrow + 0);
        *(float4*)&w0[4] = *(const float4*)(wrow + 4);
        *(float4*)&w1[0] = *(const float4*)(wrow + 8);
        *(float4*)&w1[4] = *(const float4*)(wrow + 12);
        *(float4*)&w2[0] = *(const float4*)(wrow + 16);
        *(float4*)&w2[4] = *(const float4*)(wrow + 20);
        *(float4*)&w3[0] = *(const float4*)(wrow + 24);
        *(float4*)&w3[4] = *(const float4*)(wrow + 28);

        float s2 = v.x + v.y;
#pragma unroll
        for (int c = 0; c < 8; c++) {
            a3[0][c] = fmaf(w3[c], v.x, a3[0][c]);
            a3[1][c] = fmaf(w3[c], v.y, a3[1][c]);
            a2[c]    = fmaf(w2[c], s2, a2[c]);
            a1[c]    = fmaf(w1[c], s2, a1[c]);
            a0[c]    = fmaf(w0[c], s2, a0[c]);
        }
    }

    __syncthreads();

    {
        float (*red)[16][64] = (float (*)[16][64])smem;
#pragma unroll
        for (int pos = 0; pos < 2; pos++)
#pragma unroll
            for (int c = 0; c < 8; c++)
                red[wv][pos * 8 + c][lane] = a3[pos][c];
        __syncthreads();
        for (int o = tid; o < 1024; o += 512) {
            int ln = o & 63, s = o >> 6;
            float sum = 0.f;
#pragma unroll
            for (int w = 0; w < 8; w++) sum += red[w][s][ln];
            int pos = s >> 3, c = s & 7;
            int tp = t0 + ln * 2 + pos;
            ws[WS_P3 + ((long long)b * 4096 + tp) * 8 + c] = sum + in_b[3 * 8 + c];
        }
        __syncthreads();
    }

    {
        float (*red)[24][64] = (float (*)[24][64])smem;
#pragma unroll
        for (int c = 0; c < 8; c++) {
            red[wv][c][lane]      = a2[c];
            red[wv][8 + c][lane]  = a1[c];
            red[wv][16 + c][lane] = a0[c];
        }
        __syncthreads();
        for (int o = tid; o < 1536; o += 512) {
            int ln = o & 63, s = o >> 6;
            if (s < 8) {
                int c = s;
                float sum = 0.f;
#pragma unroll
                for (int w = 0; w < 8; w++) sum += red[w][s][ln];
                int tp = (t0 >> 1) + ln;
                ws[WS_P2 + ((long long)b * 2048 + tp) * 8 + c] = sum * 0.5f + in_b[2 * 8 + c];
            } else if (s < 16) {
                if (ln >= 32) continue;
                int c = s - 8;
                float sum = 0.f;
#pragma unroll
                for (int w = 0; w < 8; w++) sum += red[w][s][2 * ln] + red[w][s][2 * ln + 1];
                int tp = (t0 >> 2) + ln;
                ws[WS_P1 + ((long long)b * 1024 + tp) * 8 + c] = sum * 0.25f + in_b[8 + c];
            } else {
                if (ln >= 16) continue;
                int c = s - 16;
                float sum = 0.f;
#pragma unroll
                for (int w = 0; w < 8; w++)
#pragma unroll
                    for (int k = 0; k < 4; k++) sum += red[w][s][4 * ln + k];
                int tp = (t0 >> 3) + ln;
                ws[WS_P0 + ((long long)b * 512 + tp) * 8 + c] = sum * 0.125f + in_b[c];
            }
        }
    }
}

// ---------------------------------------------------------------------------
// k_vq<S> v3: block = 64 vectors x 8 waves (512 thr). Codebook records
// staged in LDS (48KB) -> scan is LDS-broadcast-fed, VALU-bound. e from P
// minus table gathers (f64 accumulate of f32 table rows; indices read back
// from codes written by earlier stages). First-index tie rules preserved.
// 53KB LDS -> 3 blocks/CU, 24 waves/CU.
// ---------------------------------------------------------------------------
template <int S>
__global__ __launch_bounds__(512) void k_vq(
    const float* __restrict__ cb, float* __restrict__ ws, float* __restrict__ out)
{
    constexpr int TS = 512 << S;
    constexpr long long PBASE = (S == 0) ? WS_P0 : (S == 1) ? WS_P1 : (S == 2) ? WS_P2 : WS_P3;
    constexpr long long QBASE = (S == 0) ? WS_Q0 : (S == 1) ? WS_Q1 : (S == 2) ? WS_Q2 : WS_Q3;
    constexpr int pbase = (S == 1) ? 0 : (S == 2) ? 1 : 3;
    constexpr float LW = 1.0f / (8.0f * (float)TS * (float)B);

    __shared__ float cbl[12288];            // 48 KB: this stage's records
    __shared__ float sb[8][64];
    __shared__ unsigned short si[8][64];
    __shared__ float e_lds[64][8];

    int tid = threadIdx.x;
    int lane = tid & 63;
    int w = __builtin_amdgcn_readfirstlane(tid >> 6);

    // stage records -> LDS (float4, coalesced)
    {
        const float4* src = (const float4*)(ws + WS_CBREC + (long long)S * K * 12);
        float4* dst = (float4*)cbl;
        for (int o = tid; o < 3072; o += 512) dst[o] = src[o];
    }

    long long v = (long long)blockIdx.x * 64 + lane;
    int b = (int)(v >> (9 + S));
    int tp = (int)(v & (TS - 1));

    // e = P - table gathers
    float e[8];
    const float* P = ws + PBASE + v * 8;
#pragma unroll
    for (int c = 0; c < 8; c++) e[c] = P[c];

    if (S > 0) {
        double ed[8];
#pragma unroll
        for (int c = 0; c < 8; c++) ed[c] = (double)e[c];
#pragma unroll
        for (int j = 0; j < S; j++) {
            int tj = tp >> (S - j);
            long long vj = ((long long)b << (9 + j)) + tj;
            int cidx = (int)out[code_off(j) + vj];
            const float* trow = ws + WS_TAB + ((long long)(pbase + j) * 1024 + cidx) * 8;
#pragma unroll
            for (int c = 0; c < 8; c++) ed[c] -= (double)trow[c];
        }
#pragma unroll
        for (int c = 0; c < 8; c++) e[c] = (float)ed[c];
    }

    // normalize (F.normalize: x / max(||x||, 1e-12))
    float n2 = 0.f;
#pragma unroll
    for (int c = 0; c < 8; c++) n2 = fmaf(e[c], e[c], n2);
    float den = fmaxf(sqrtf(n2), 1e-12f);
    float inv = 1.0f / den;
    float en[8];
#pragma unroll
    for (int c = 0; c < 8; c++) en[c] = e[c] * inv;

    if (w == 0) {
#pragma unroll
        for (int c = 0; c < 8; c++) e_lds[lane][c] = e[c];
    }

    __syncthreads();   // cbl + e_lds ready

    // scan this wave's 128-code chunk from LDS (en2 const -> dropped)
    const float* rec = cbl + w * 128 * 12;
    float best = 3.0e38f;
    int bidx = 0;
    for (int jt = 0; jt < 128; jt++) {
        const float* r = rec + jt * 12;
        float acc = r[8];                       // cn2
#pragma unroll
        for (int c = 0; c < 8; c++) acc = fmaf(r[c], en[c], acc);  // - 2*dot
        if (acc < best) { best = acc; bidx = jt; }
    }
    sb[w][lane] = best;
    si[w][lane] = (unsigned short)(w * 128 + bidx);
    __syncthreads();

    if (tid < 64) {
        float bd = sb[0][lane];
        int bj = si[0][lane];
#pragma unroll
        for (int ww = 1; ww < 8; ww++) {
            float d2 = sb[ww][lane];
            int j2 = si[ww][lane];
            if (d2 < bd || (d2 == bd && j2 < bj)) { bd = d2; bj = j2; }
        }
        // unnormalized codebook lookup
        const float* qc = cb + ((long long)S * K + bj) * 8;
        float qv[8];
#pragma unroll
        for (int c = 0; c < 8; c++) qv[c] = qc[c];
        float* qo = ws + QBASE + v * 8;
#pragma unroll
        for (int c = 0; c < 8; c++) qo[c] = qv[c];

        out[code_off(S) + v] = (float)bj;

        // commit/cb loss (identical values)
        float l = 0.f;
#pragma unroll
        for (int c = 0; c < 8; c++) { float dq = e[c] - qv[c]; l = fmaf(dq, dq, l); }
#pragma unroll
        for (int off = 32; off >= 1; off >>= 1) l += __shfl_down(l, off);
        if (lane == 0) atomicAdd(ws + WS_LOSS, l * LW);
    }

    // cooperative coalesced latents write
    constexpr int SREP = 8 >> S;
    {
        long long v0 = (long long)blockIdx.x * 64;
        int b0 = (int)(v0 >> (9 + S));
        int tp0 = (int)(v0 & (TS - 1));
        long long lat0 = OUT_LAT + ((long long)b0 * 32 + S * 8) * T + (long long)tp0 * SREP;
        for (int o = tid; o < 512 * SREP; o += 512) {
            int c = o / (64 * SREP);
            int r = o & (64 * SREP - 1);
            out[lat0 + (long long)c * T + r] = e_lds[r / SREP][c];
        }
    }
}

// ---------------------------------------------------------------------------
// k_zq (unchanged from R4): lane owns 4 t -> float4 stores; 4096 blocks.
// ---------------------------------------------------------------------------
__global__ __launch_bounds__(256) void k_zq(
    const float* __restrict__ out_w, const float* __restrict__ ws, float* __restrict__ out)
{
    int tid = threadIdx.x;
    int lane = tid & 63;
    int w = __builtin_amdgcn_readfirstlane(tid >> 6);
    int bid = blockIdx.x;                 // 4096 = 16 b * 64 dgrp * 4 tchunk
    int tc   = bid & 3;
    int g    = (bid >> 2) & 63;
    int b    = bid >> 8;
    int t    = tc * 1024 + w * 256 + lane * 4;

    float q0[8], q1[8], q2[2][8], q3[4][8];
    {
        const float* Q = ws + WS_Q0 + ((long long)b * 512 + (t >> 3)) * 8;
#pragma unroll
        for (int c = 0; c < 8; c++) q0[c] = Q[c];
    }
    {
        const float* Q = ws + WS_Q1 + ((long long)b * 1024 + (t >> 2)) * 8;
#pragma unroll
        for (int c = 0; c < 8; c++) q1[c] = Q[c];
    }
    {
        const float* Q = ws + WS_Q2 + ((long long)b * 2048 + (t >> 1)) * 8;
#pragma unroll
        for (int j = 0; j < 2; j++)
#pragma unroll
            for (int c = 0; c < 8; c++) q2[j][c] = Q[j * 8 + c];
    }
    {
        const float* Q = ws + WS_Q3 + ((long long)b * 4096 + t) * 8;
#pragma unroll
        for (int j = 0; j < 4; j++)
#pragma unroll
            for (int c = 0; c < 8; c++) q3[j][c] = Q[j * 8 + c];
    }

#pragma unroll 2
    for (int dl = 0; dl < 8; dl++) {
        int d = g * 8 + dl;
        const float* w0 = out_w + 0 * 4096 + d * 8;
        const float* w1 = out_w + 1 * 4096 + d * 8;
        const float* w2 = out_w + 2 * 4096 + d * 8;
        const float* w3 = out_w + 3 * 4096 + d * 8;

        float acc = ws[WS_OBS + d];
#pragma unroll
        for (int c = 0; c < 8; c++) acc = fmaf(w0[c], q0[c], acc);
#pragma unroll
        for (int c = 0; c < 8; c++) acc = fmaf(w1[c], q1[c], acc);
        float accA = acc, accB = acc;
#pragma unroll
        for (int c = 0; c < 8; c++) {
            accA = fmaf(w2[c], q2[0][c], accA);
            accB = fmaf(w2[c], q2[1][c], accB);
        }
        float r0 = accA, r1 = accA, r2 = accB, r3 = accB;
#pragma unroll
        for (int c = 0; c < 8; c++) {
            r0 = fmaf(w3[c], q3[0][c], r0);
            r1 = fmaf(w3[c], q3[1][c], r1);
            r2 = fmaf(w3[c], q3[2][c], r2);
            r3 = fmaf(w3[c], q3[3][c], r3);
        }
        float* o = out + OUT_ZQ + ((long long)b * 512 + d) * T + t;
        *(float4*)o = make_float4(r0, r1, r2, r3);
    }

    if (bid == 0 && tid == 0) {
        float L = ws[WS_LOSS];
        out[OUT_COMMIT] = L;
        out[OUT_CBL]    = L;
    }
}

// ---------------------------------------------------------------------------
extern "C" void kernel_launch(void* const* d_in, const int* in_sizes, int n_in,
                              void* d_out, int out_size, void* d_ws, size_t ws_size,
                              hipStream_t stream)
{
    const float* z     = (const float*)d_in[0];
    const float* in_w  = (const float*)d_in[1];
    const float* in_b  = (const float*)d_in[2];
    const float* out_w = (const float*)d_in[3];
    const float* out_b = (const float*)d_in[4];
    const float* cb    = (const float*)d_in[5];
    float* out = (float*)d_out;
    float* ws  = (float*)d_ws;

    k_prep<<<dim3(126), dim3(256), 0, stream>>>(in_w, out_w, out_b, cb, ws);
    k_prep_c<<<dim3(24), dim3(256), 0, stream>>>(cb, ws);
    k_pool_proj<<<dim3(16, 32), dim3(512), 0, stream>>>(z, in_w, in_b, ws);
    k_vq<0><<<dim3(128), dim3(512), 0, stream>>>(cb, ws, out);
    k_vq<1><<<dim3(256), dim3(512), 0, stream>>>(cb, ws, out);
    k_vq<2><<<dim3(512), dim3(512), 0, stream>>>(cb, ws, out);
    k_vq<3><<<dim3(1024), dim3(512), 0, stream>>>(cb, ws, out);
    k_zq<<<dim3(4096), dim3(256), 0, stream>>>(out_w, ws, out);
}